// Round 7
// baseline (344.611 us; speedup 1.0000x reference)
//
#include <hip/hip_runtime.h>
#include <cstdint>

// DynamicConvAttention: B=4, S=2048, D=1024, NH=16 (groups), K=3
// f32 I/O, bf16 MFMA internal. 7 launches (primary path).
//
// r15: K-plane GEMM DELETED via weight folding.
//   S = Q·K^T = x·(Wq Wk^T)·x^T + kv,  kv[k] = x[k]·(Wk·bq)
//   G[e,d] = sum_j Wk[e,j]·Wq[d,j]  (1024x1024 bf16, 64 tiles)
//   xq'    = xb·G^T  (replaces Q-plane; bias folded into kv)
//   scores = xq'·xb^T + kv  (B-operand is xb -> K never materialized)
// Launches: prep | vg_kv {V->vt, G, kv} (640 blk = 1 round) | xq' (512)
//           | scores (1024) | pv_conv | ln2 | out.
// P batches 0,1 relocate to freed Kb (16 MiB exact). xb stays live
// through scores (P no longer lands in d_out[0:16MiB)).
// r13/r14 kept: unnormalized-exp softmax (P'=exp(s/32), f32 rowsum via
// atomics, normalize in PV epilogue); V written transposed by its GEMM.
//
// ws: wT[0,8M) (G overwrites slot0 in primary) | qkvb[8M,+12K) | wb +4K
//     | rsum[8M+16K,+32K) | kv[8M+48K,+32K) | Q[9M,25M) | Kb[25M,41M)
//     (P b0,1) | Vb[41M,57M) (conv) | Pw[57M,73M) (P b2,3; Wq_o/Wk_o early)
// d_out: xb[0,16Mi) | vt[16Mi,32Mi)

#define DEV __device__ __forceinline__

typedef unsigned short u16;
typedef __attribute__((ext_vector_type(8))) short bf16x8;
typedef __attribute__((ext_vector_type(4))) float f32x4;

static const int Sn = 2048, Dn = 1024;

DEV float bf2f(u16 u) { union { unsigned int i; float f; } w; w.i = ((unsigned int)u) << 16; return w.f; }
DEV u16 f2bf(float f) {
  union { float f; unsigned int i; } w; w.f = f;
  unsigned int x = w.i;
  return (u16)((x + 0x7FFFu + ((x >> 16) & 1u)) >> 16);
}

DEV void gload_lds16(const u16* gsrc, u16* lds_dst) {
  __builtin_amdgcn_global_load_lds(
      (const __attribute__((address_space(1))) void*)gsrc,
      (__attribute__((address_space(3))) void*)lds_dst,
      16, 0, 0);
}

DEV float block_allreduce_sum(float v, float* red, int tid) {
  #pragma unroll
  for (int o = 32; o > 0; o >>= 1) v += __shfl_down(v, o, 64);
  __syncthreads();
  if ((tid & 63) == 0) red[tid >> 6] = v;
  __syncthreads();
  return red[0] + red[1] + red[2] + red[3];
}

DEV float block_allreduce_max(float v, float* red, int tid) {
  #pragma unroll
  for (int o = 32; o > 0; o >>= 1) v = fmaxf(v, __shfl_down(v, o, 64));
  __syncthreads();
  if ((tid & 63) == 0) red[tid >> 6] = v;
  __syncthreads();
  return fmaxf(fmaxf(red[0], red[1]), fmaxf(red[2], red[3]));
}

// ======= prep_all: wT + bias + rsum0 + x cvt + Wq/Wk plain cvt + wb ========
// [0,1024)       : weight transpose+cvt (4 weights x 256 tiles)
// 1024           : qkv bias concat + rsum zero
// [1025,9217)    : x f32->bf16
// [9217,11265)   : Wq/Wk plain f32->bf16 (wqo, wko)
// [11265,11281)  : wb = Wk . bq  (16 blocks x 64 rows)
__global__ __launch_bounds__(256)
void prep_all(const float* __restrict__ Wq, const float* __restrict__ Wk,
              const float* __restrict__ Wv, const float* __restrict__ Wo,
              u16* __restrict__ wT,
              const float* __restrict__ bq, const float* __restrict__ bv,
              float* __restrict__ qkvb, float* __restrict__ rowsum,
              const float* __restrict__ x, u16* __restrict__ xb,
              u16* __restrict__ wqo, u16* __restrict__ wko,
              float* __restrict__ wbout) {
  __shared__ u16 sm[64][68];
  int blk = blockIdx.x;
  int tid = threadIdx.x;
  if (blk < 1024) {
    int w = blk >> 8, t = blk & 255;
    const float* src = (w == 0) ? Wq : (w == 1) ? Wk : (w == 2) ? Wv : Wo;
    u16* dst = wT + (size_t)w * 1048576u;
    int i0 = (t >> 4) << 6, j0 = (t & 15) << 6;
    int tx = tid & 15, r0 = tid >> 4;
    #pragma unroll
    for (int rr = r0; rr < 64; rr += 16) {
      float4 v = *(const float4*)&src[(long)(i0 + rr) * 1024 + j0 + tx * 4];
      sm[rr][tx*4+0] = f2bf(v.x); sm[rr][tx*4+1] = f2bf(v.y);
      sm[rr][tx*4+2] = f2bf(v.z); sm[rr][tx*4+3] = f2bf(v.w);
    }
    __syncthreads();
    #pragma unroll
    for (int cc = r0; cc < 64; cc += 16) {
      ushort4 o;
      o.x = sm[tx*4+0][cc]; o.y = sm[tx*4+1][cc];
      o.z = sm[tx*4+2][cc]; o.w = sm[tx*4+3][cc];
      *(ushort4*)&dst[(long)(j0 + cc) * 1024 + i0 + tx * 4] = o;
    }
  } else if (blk == 1024) {
    for (int j = tid; j < 3072; j += 256) {
      float v = 0.0f;
      if (j < 1024) v = bq[j];
      else if (j >= 2048) v = bv[j - 2048];
      qkvb[j] = v;
    }
    for (int j = tid; j < 8192; j += 256) rowsum[j] = 0.0f;
  } else if (blk < 9217) {
    int i = (blk - 1025) * 1024 + tid * 4;
    float4 v = *(const float4*)&x[i];
    ushort4 o;
    o.x = f2bf(v.x); o.y = f2bf(v.y); o.z = f2bf(v.z); o.w = f2bf(v.w);
    *(ushort4*)&xb[i] = o;
  } else if (blk < 11265) {
    int idx = blk - 9217;
    int w = idx >> 10;
    long i = (long)(idx & 1023) * 1024 + tid * 4;
    const float* src = w ? Wk : Wq;
    u16* dst = w ? wko : wqo;
    float4 v = *(const float4*)&src[i];
    ushort4 o;
    o.x = f2bf(v.x); o.y = f2bf(v.y); o.z = f2bf(v.z); o.w = f2bf(v.w);
    *(ushort4*)&dst[i] = o;
  } else {
    // wb[e] = sum_j Wk[e,j] * bq[j]
    int t = blk - 11265;
    int lane = tid & 63, wv2 = tid >> 6;
    for (int rr = 0; rr < 16; rr++) {
      int e = t * 64 + wv2 * 16 + rr;
      const float* wr = Wk + (long)e * 1024 + lane * 16;
      const float* br = bq + lane * 16;
      float s = 0.0f;
      #pragma unroll
      for (int j = 0; j < 16; j += 4) {
        float4 a4 = *(const float4*)&wr[j];
        float4 b4 = *(const float4*)&br[j];
        s += a4.x * b4.x + a4.y * b4.y + a4.z * b4.z + a4.w * b4.w;
      }
      #pragma unroll
      for (int o = 32; o > 0; o >>= 1) s += __shfl_down(s, o, 64);
      if (lane == 0) wbout[e] = s;
    }
  }
}

// ================= NT GEMM, BK=64 split-halves (proven r7 core) ============
// vtout: if non-null and z==2 (bf16 out), epilogue writes tile TRANSPOSED
// into vtout[b][d][s] (fallback V^T path and r14 primary; xq'/out pass null).
template<typename CT>
__global__ __launch_bounds__(256, 2)
void gemm_nt(const u16* __restrict__ A, const u16* __restrict__ A2, long Abs, int lda,
             const u16* __restrict__ B, long Bbs, int ldb,
             CT* __restrict__ C, CT* __restrict__ C2, long Cbs, int ldc,
             int zsplit, int K, float scale,
             const float* __restrict__ bias, int bias_bs,
             const float* __restrict__ res, long Rbs, int ldr,
             u16* __restrict__ vtout) {
  __shared__ u16 sA[2][128 * 32];
  __shared__ u16 sB[2][128 * 32];
  int tid = threadIdx.x;
  int lane = tid & 63, wv = tid >> 6;
  int quad = lane >> 4, lm = lane & 15;
  int wr = wv >> 1, wc = wv & 1;
  long m0 = (long)blockIdx.x * 128, n0 = (long)blockIdx.y * 128;
  int z = blockIdx.z;
  if (z >= zsplit) { A = A2 + (long)(z - zsplit) * Abs; C = C2 + (long)(z - zsplit) * Cbs; }
  else             { A = A  + (long)z * Abs;            C = C  + (long)z * Cbs; }
  B += (long)z * Bbs;
  if (res) res += (long)z * Rbs;

  f32x4 acc[4][4] = {};

  int srow = wv * 16 + (lane >> 2);
  int sch = (lane & 3) * 8;
  const u16* Ap = A + (m0 + srow) * (long)lda + sch;
  const u16* Bp = B + (n0 + srow) * (long)ldb + sch;
  const int lofs = wv * 16 * 32;

  for (int k0 = 0; k0 < K; k0 += 64) {
    #pragma unroll
    for (int h = 0; h < 2; h++) {
      int kh = k0 + h * 32;
      gload_lds16(Ap + kh, &sA[h][lofs]);
      gload_lds16(Ap + 64 * (long)lda + kh, &sA[h][lofs + 64 * 32]);
      gload_lds16(Bp + kh, &sB[h][lofs]);
      gload_lds16(Bp + 64 * (long)ldb + kh, &sB[h][lofs + 64 * 32]);
    }
    __syncthreads();
    #pragma unroll
    for (int h = 0; h < 2; h++) {
      bf16x8 af[4], bfr[4];
      #pragma unroll
      for (int mi = 0; mi < 4; mi++)
        af[mi] = *(const bf16x8*)&sA[h][(wr * 64 + mi * 16 + lm) * 32 + quad * 8];
      #pragma unroll
      for (int ni = 0; ni < 4; ni++)
        bfr[ni] = *(const bf16x8*)&sB[h][(wc * 64 + ni * 16 + lm) * 32 + quad * 8];
      #pragma unroll
      for (int mi = 0; mi < 4; mi++)
        #pragma unroll
        for (int ni = 0; ni < 4; ni++)
          acc[mi][ni] = __builtin_amdgcn_mfma_f32_16x16x32_bf16(af[mi], bfr[ni], acc[mi][ni], 0, 0, 0);
    }
    __syncthreads();
  }

  if (sizeof(CT) == 2 && vtout && z == 2) {
    int b = (int)(m0 >> 11);
    long s0 = (m0 & 2047) + wr * 64 + quad * 4;
    #pragma unroll
    for (int ni = 0; ni < 4; ni++) {
      int col = (int)n0 + wc * 64 + ni * 16 + lm;
      float bv = bias ? bias[(long)z * bias_bs + col] : 0.0f;
      u16* vrow = vtout + ((long)b * 1024 + col) * 2048;
      #pragma unroll
      for (int mi = 0; mi < 4; mi++) {
        ushort4 o;
        o.x = f2bf(acc[mi][ni][0] * scale + bv);
        o.y = f2bf(acc[mi][ni][1] * scale + bv);
        o.z = f2bf(acc[mi][ni][2] * scale + bv);
        o.w = f2bf(acc[mi][ni][3] * scale + bv);
        *(ushort4*)&vrow[s0 + mi * 16] = o;
      }
    }
  } else {
    #pragma unroll
    for (int mi = 0; mi < 4; mi++) {
      #pragma unroll
      for (int ni = 0; ni < 4; ni++) {
        int col = (int)n0 + wc * 64 + ni * 16 + lm;
        float bv = bias ? bias[(long)z * bias_bs + col] : 0.0f;
        #pragma unroll
        for (int r = 0; r < 4; r++) {
          long rowg = m0 + wr * 64 + mi * 16 + quad * 4 + r;
          float v = acc[mi][ni][r] * scale + bv;
          if (res) v += res[rowg * (long)ldr + col];
          if constexpr (sizeof(CT) == 2) C[rowg * (long)ldc + col] = f2bf(v);
          else                           C[rowg * (long)ldc + col] = v;
        }
      }
    }
  }
}

// ====== vg_kv: V-GEMM (->vt transposed) + G-GEMM + kv riders, one launch ===
// [0,512)   : V tile (m0=(blk&63)*128 of x-rows, n0=(blk>>6)*128 of V cols)
// [512,576) : G tile (64 tiles of 1024x1024; G[e,d]=sum_j Wk[e,j]Wq[d,j])
// [576,640) : kv rows (128 rows/block): kv[r] = dot(xb[r], wb)
__global__ __launch_bounds__(256, 2)
void vg_kv(const u16* __restrict__ xb, const u16* __restrict__ wvT,
           const u16* __restrict__ wqo, const u16* __restrict__ wko,
           const float* __restrict__ bv,
           u16* __restrict__ vt, u16* __restrict__ G,
           const float* __restrict__ wb, float* __restrict__ kv) {
  __shared__ u16 sA[2][128 * 32];
  __shared__ u16 sB[2][128 * 32];
  int blk = blockIdx.x;
  int tid = threadIdx.x;
  if (blk < 576) {
    bool isV = blk < 512;
    long m0, n0;
    const u16 *A, *B;
    if (isV) { m0 = (long)(blk & 63) * 128; n0 = (long)(blk >> 6) * 128; A = xb; B = wvT; }
    else { int t = blk - 512; m0 = (long)(t & 7) * 128; n0 = (long)(t >> 3) * 128; A = wko; B = wqo; }
    int lane = tid & 63, wv = tid >> 6;
    int quad = lane >> 4, lm = lane & 15;
    int wr = wv >> 1, wc = wv & 1;
    f32x4 acc[4][4] = {};
    int srow = wv * 16 + (lane >> 2);
    int sch = (lane & 3) * 8;
    const u16* Ap = A + (m0 + srow) * 1024 + sch;
    const u16* Bp = B + (n0 + srow) * 1024 + sch;
    const int lofs = wv * 16 * 32;
    for (int k0 = 0; k0 < 1024; k0 += 64) {
      #pragma unroll
      for (int h = 0; h < 2; h++) {
        int kh = k0 + h * 32;
        gload_lds16(Ap + kh, &sA[h][lofs]);
        gload_lds16(Ap + 64 * 1024 + kh, &sA[h][lofs + 64 * 32]);
        gload_lds16(Bp + kh, &sB[h][lofs]);
        gload_lds16(Bp + 64 * 1024 + kh, &sB[h][lofs + 64 * 32]);
      }
      __syncthreads();
      #pragma unroll
      for (int h = 0; h < 2; h++) {
        bf16x8 af[4], bfr[4];
        #pragma unroll
        for (int mi = 0; mi < 4; mi++)
          af[mi] = *(const bf16x8*)&sA[h][(wr * 64 + mi * 16 + lm) * 32 + quad * 8];
        #pragma unroll
        for (int ni = 0; ni < 4; ni++)
          bfr[ni] = *(const bf16x8*)&sB[h][(wc * 64 + ni * 16 + lm) * 32 + quad * 8];
        #pragma unroll
        for (int mi = 0; mi < 4; mi++)
          #pragma unroll
          for (int ni = 0; ni < 4; ni++)
            acc[mi][ni] = __builtin_amdgcn_mfma_f32_16x16x32_bf16(af[mi], bfr[ni], acc[mi][ni], 0, 0, 0);
      }
      __syncthreads();
    }
    if (isV) {
      int b = (int)(m0 >> 11);
      long s0 = (m0 & 2047) + wr * 64 + quad * 4;
      #pragma unroll
      for (int ni = 0; ni < 4; ni++) {
        int col = (int)n0 + wc * 64 + ni * 16 + lm;
        float bvv = bv[col];
        u16* vrow = vt + ((long)b * 1024 + col) * 2048;
        #pragma unroll
        for (int mi = 0; mi < 4; mi++) {
          ushort4 o;
          o.x = f2bf(acc[mi][ni][0] + bvv);
          o.y = f2bf(acc[mi][ni][1] + bvv);
          o.z = f2bf(acc[mi][ni][2] + bvv);
          o.w = f2bf(acc[mi][ni][3] + bvv);
          *(ushort4*)&vrow[s0 + mi * 16] = o;
        }
      }
    } else {
      #pragma unroll
      for (int mi = 0; mi < 4; mi++) {
        #pragma unroll
        for (int ni = 0; ni < 4; ni++) {
          int col = (int)n0 + wc * 64 + ni * 16 + lm;
          #pragma unroll
          for (int r = 0; r < 4; r++) {
            long rowg = m0 + wr * 64 + mi * 16 + quad * 4 + r;
            G[rowg * 1024 + col] = f2bf(acc[mi][ni][r]);
          }
        }
      }
    }
  } else {
    // kv: 64 blocks x 128 rows; per row: 64-lane dot + shuffle reduce
    int t = blk - 576;
    int lane = tid & 63, wv2 = tid >> 6;
    for (int rr = 0; rr < 32; rr++) {
      long row = (long)t * 128 + wv2 * 32 + rr;
      const u16* xr = xb + row * 1024 + lane * 16;
      const float* wr = wb + lane * 16;
      float s = 0.0f;
      #pragma unroll
      for (int j = 0; j < 16; j += 4) {
        ushort4 v = *(const ushort4*)&xr[j];
        float4 w4 = *(const float4*)&wr[j];
        s += bf2f(v.x) * w4.x + bf2f(v.y) * w4.y + bf2f(v.z) * w4.z + bf2f(v.w) * w4.w;
      }
      #pragma unroll
      for (int o = 32; o > 0; o >>= 1) s += __shfl_down(s, o, 64);
      if (lane == 0) kv[row] = s;
    }
  }
}

// ============ post_qkv: scores GEMM (exp + kv + rowsum) [+V^T fallback] ====
// blocks [0, ngemm) : scores tile: S = A.B^T; epilogue writes
//                     P' = exp((s + kv[col])/32), rowsum atomics.
// blocks [ngemm,..) : V^T 64x64 tiles (FALLBACK ONLY)
__global__ __launch_bounds__(256, 2)
void post_qkv(int ngemm,
              const u16* __restrict__ Qb, const u16* __restrict__ Bx,
              u16* __restrict__ Pd, u16* __restrict__ Pw,
              const u16* __restrict__ Vb, u16* __restrict__ vt,
              float* __restrict__ rowsum, const float* __restrict__ kv) {
  __shared__ u16 smem[2 * 2 * 128 * 32];  // 32 KB
  int blk = blockIdx.x;
  int tid = threadIdx.x;
  if (blk < ngemm) {
    u16* sA0 = smem;
    u16* sB0 = smem + 2 * 128 * 32;
    int lane = tid & 63, wv = tid >> 6;
    int quad = lane >> 4, lm = lane & 15;
    int wr = wv >> 1, wc = wv & 1;
    int z = blk >> 8;
    long m0 = (long)(blk & 15) * 128, n0 = (long)((blk >> 4) & 15) * 128;
    const u16* A = Qb + (long)z * Sn * Dn;
    const u16* B = Bx + (long)z * Sn * Dn;
    u16* C = (z < 2) ? Pd + (long)z * Sn * Sn : Pw + (long)(z - 2) * Sn * Sn;

    f32x4 acc[4][4] = {};
    int srow = wv * 16 + (lane >> 2);
    int sch = (lane & 3) * 8;
    const u16* Ap = A + (m0 + srow) * 1024 + sch;
    const u16* Bp = B + (n0 + srow) * 1024 + sch;
    const int lofs = wv * 16 * 32;

    for (int k0 = 0; k0 < 1024; k0 += 64) {
      #pragma unroll
      for (int h = 0; h < 2; h++) {
        int kh = k0 + h * 32;
        gload_lds16(Ap + kh, &sA0[h * 128 * 32 + lofs]);
        gload_lds16(Ap + 64 * 1024 + kh, &sA0[h * 128 * 32 + lofs + 64 * 32]);
        gload_lds16(Bp + kh, &sB0[h * 128 * 32 + lofs]);
        gload_lds16(Bp + 64 * 1024 + kh, &sB0[h * 128 * 32 + lofs + 64 * 32]);
      }
      __syncthreads();
      #pragma unroll
      for (int h = 0; h < 2; h++) {
        bf16x8 af[4], bfr[4];
        #pragma unroll
        for (int mi = 0; mi < 4; mi++)
          af[mi] = *(const bf16x8*)&sA0[h * 128 * 32 + (wr * 64 + mi * 16 + lm) * 32 + quad * 8];
        #pragma unroll
        for (int ni = 0; ni < 4; ni++)
          bfr[ni] = *(const bf16x8*)&sB0[h * 128 * 32 + (wc * 64 + ni * 16 + lm) * 32 + quad * 8];
        #pragma unroll
        for (int mi = 0; mi < 4; mi++)
          #pragma unroll
          for (int ni = 0; ni < 4; ni++)
            acc[mi][ni] = __builtin_amdgcn_mfma_f32_16x16x32_bf16(af[mi], bfr[ni], acc[mi][ni], 0, 0, 0);
      }
      __syncthreads();
    }
    float kvv[4];
    #pragma unroll
    for (int ni = 0; ni < 4; ni++) {
      int col = (int)n0 + wc * 64 + ni * 16 + lm;
      kvv[ni] = kv ? kv[(long)z * 2048 + col] : 0.0f;
    }
    float psum[4][4];
    #pragma unroll
    for (int mi = 0; mi < 4; mi++)
      #pragma unroll
      for (int r = 0; r < 4; r++) psum[mi][r] = 0.0f;
    #pragma unroll
    for (int mi = 0; mi < 4; mi++) {
      #pragma unroll
      for (int ni = 0; ni < 4; ni++) {
        int col = (int)n0 + wc * 64 + ni * 16 + lm;
        #pragma unroll
        for (int r = 0; r < 4; r++) {
          long rowg = m0 + wr * 64 + mi * 16 + quad * 4 + r;
          float e = __expf((acc[mi][ni][r] + kvv[ni]) * 0.03125f);
          psum[mi][r] += e;
          C[rowg * 2048 + col] = f2bf(e);
        }
      }
    }
    #pragma unroll
    for (int mi = 0; mi < 4; mi++)
      #pragma unroll
      for (int r = 0; r < 4; r++) {
        float v = psum[mi][r];
        v += __shfl_xor(v, 1, 64);
        v += __shfl_xor(v, 2, 64);
        v += __shfl_xor(v, 4, 64);
        v += __shfl_xor(v, 8, 64);
        psum[mi][r] = v;
      }
    if (lm == 0) {
      #pragma unroll
      for (int mi = 0; mi < 4; mi++)
        #pragma unroll
        for (int r = 0; r < 4; r++) {
          long rowg = m0 + wr * 64 + mi * 16 + quad * 4 + r;
          unsafeAtomicAdd(&rowsum[(long)z * 2048 + rowg], psum[mi][r]);
        }
    }
  } else {
    u16 (*sm)[68] = (u16(*)[68])smem;
    int t = blk - ngemm;
    int b = t >> 9, r = t & 511;
    int j0 = (r & 15) << 6, i0 = ((r >> 4) & 31) << 6;
    const u16* s = Vb + (long)b * Sn * Dn;
    u16* d = vt + (long)b * Dn * Sn;
    int tx = tid & 15, r0 = tid >> 4;
    #pragma unroll
    for (int rr = r0; rr < 64; rr += 16) {
      ushort4 v = *(const ushort4*)&s[(long)(i0 + rr) * 1024 + j0 + tx * 4];
      sm[rr][tx*4+0] = v.x; sm[rr][tx*4+1] = v.y; sm[rr][tx*4+2] = v.z; sm[rr][tx*4+3] = v.w;
    }
    __syncthreads();
    #pragma unroll
    for (int cc = r0; cc < 64; cc += 16) {
      ushort4 o;
      o.x = sm[tx*4+0][cc]; o.y = sm[tx*4+1][cc];
      o.z = sm[tx*4+2][cc]; o.w = sm[tx*4+3][cc];
      *(ushort4*)&d[(long)(j0 + cc) * 2048 + i0 + tx * 4] = o;
    }
  }
}

// ==== smax_conv: kept for fallback (softmax rows + grouped conv) ===========
__global__ __launch_bounds__(256)
void smax_conv(u16* __restrict__ pa, u16* __restrict__ pb, int rowsplit, int nsm,
               const float* __restrict__ x, const float* __restrict__ cw,
               const float* __restrict__ cb, u16* __restrict__ convo) {
  __shared__ u16 smem[22160];
  __shared__ float red[4];
  int blk = blockIdx.x;
  int tid = threadIdx.x;
  if (blk < nsm) {
    long row = blk;
    u16* p = (row < rowsplit) ? pa + row * 2048 : pb + (row - rowsplit) * 2048;
    ushort4 a = *(const ushort4*)&p[tid * 8];
    ushort4 b = *(const ushort4*)&p[tid * 8 + 4];
    float f0 = bf2f(a.x), f1 = bf2f(a.y), f2 = bf2f(a.z), f3 = bf2f(a.w);
    float f4 = bf2f(b.x), f5 = bf2f(b.y), f6 = bf2f(b.z), f7 = bf2f(b.w);
    float m = fmaxf(fmaxf(fmaxf(f0, f1), fmaxf(f2, f3)),
                    fmaxf(fmaxf(f4, f5), fmaxf(f6, f7)));
    m = block_allreduce_max(m, red, tid);
    float e0 = __expf(f0 - m), e1 = __expf(f1 - m), e2 = __expf(f2 - m), e3 = __expf(f3 - m);
    float e4 = __expf(f4 - m), e5 = __expf(f5 - m), e6 = __expf(f6 - m), e7 = __expf(f7 - m);
    float s = block_allreduce_sum(e0 + e1 + e2 + e3 + e4 + e5 + e6 + e7, red, tid);
    float inv = 1.0f / s;
    ushort4 o1, o2;
    o1.x = f2bf(e0 * inv); o1.y = f2bf(e1 * inv); o1.z = f2bf(e2 * inv); o1.w = f2bf(e3 * inv);
    o2.x = f2bf(e4 * inv); o2.y = f2bf(e5 * inv); o2.z = f2bf(e6 * inv); o2.w = f2bf(e7 * inv);
    *(ushort4*)&p[tid * 8] = o1;
    *(ushort4*)&p[tid * 8 + 4] = o2;
  } else {
    u16 (*sx)[72] = (u16(*)[72])smem;
    u16 (*sw)[200] = (u16(*)[200])(smem + 9360);
    int r = blk - nsm;
    int s0 = (r & 15) * 128;
    int g = (r >> 4) & 15;
    int b = r >> 8;
    int lane = tid & 63, wv = tid >> 6;
    int quad = lane >> 4, lm = lane & 15;
    for (int idx = tid; idx < 64 * 192; idx += 256) {
      int oc = idx / 192, k = idx - oc * 192;
      int t2 = k >> 6, i = k & 63;
      sw[oc][k] = f2bf(cw[((long)(g * 64 + oc)) * 192 + i * 3 + t2]);
    }
    for (int idx = tid; idx < 130 * 16; idx += 256) {
      int rr = idx >> 4, c4 = (idx & 15) * 4;
      int s = s0 - 1 + rr;
      ushort4 v;
      if (s >= 0 && s < Sn) {
        float4 f = *(const float4*)&x[((long)b * Sn + s) * Dn + g * 64 + c4];
        v.x = f2bf(f.x); v.y = f2bf(f.y); v.z = f2bf(f.z); v.w = f2bf(f.w);
      } else { v.x = 0; v.y = 0; v.z = 0; v.w = 0; }
      *(ushort4*)&sx[rr][c4] = v;
    }
    __syncthreads();
    f32x4 acc[2][4] = {};
    #pragma unroll
    for (int ks = 0; ks < 6; ks++) {
      int t2 = ks >> 1;
      int i0 = (ks & 1) * 32 + quad * 8;
      bf16x8 a0 = *(const bf16x8*)&sx[wv * 32 + lm + t2][i0];
      bf16x8 a1 = *(const bf16x8*)&sx[wv * 32 + 16 + lm + t2][i0];
      #pragma unroll
      for (int nf = 0; nf < 4; nf++) {
        bf16x8 bf = *(const bf16x8*)&sw[nf * 16 + lm][ks * 32 + quad * 8];
        acc[0][nf] = __builtin_amdgcn_mfma_f32_16x16x32_bf16(a0, bf, acc[0][nf], 0, 0, 0);
        acc[1][nf] = __builtin_amdgcn_mfma_f32_16x16x32_bf16(a1, bf, acc[1][nf], 0, 0, 0);
      }
    }
    #pragma unroll
    for (int mi = 0; mi < 2; mi++) {
      #pragma unroll
      for (int nf = 0; nf < 4; nf++) {
        int col = g * 64 + nf * 16 + lm;
        float bias = cb[col];
        #pragma unroll
        for (int rr = 0; rr < 4; rr++) {
          int row = wv * 32 + mi * 16 + quad * 4 + rr;
          convo[((long)b * Sn + s0 + row) * Dn + col] = f2bf(acc[mi][nf][rr] + bias);
        }
      }
    }
  }
}

// ============ pv_conv: PV GEMM (normalize epilogue) + conv riders ==========
__global__ __launch_bounds__(256, 2)
void pv_conv(int npv,
             const u16* __restrict__ Pd, const u16* __restrict__ Pw,
             const u16* __restrict__ vt, u16* __restrict__ attn,
             const float* __restrict__ rowsum,
             const float* __restrict__ x, const float* __restrict__ cw,
             const float* __restrict__ cb, u16* __restrict__ convo) {
  __shared__ u16 smem[22160];  // gemm uses first 16384 u16; conv uses 22160
  int blk = blockIdx.x;
  int tid = threadIdx.x;
  if (blk < npv) {
    u16* sA0 = smem;
    u16* sB0 = smem + 2 * 128 * 32;
    int lane = tid & 63, wv = tid >> 6;
    int quad = lane >> 4, lm = lane & 15;
    int wr = wv >> 1, wc = wv & 1;
    int z = blk >> 7;
    long m0 = (long)(blk & 15) * 128, n0 = (long)((blk >> 4) & 7) * 128;
    const u16* A = (z < 2) ? Pd + (long)z * Sn * Sn : Pw + (long)(z - 2) * Sn * Sn;
    const u16* B = vt + (long)z * Dn * Sn;
    u16* C = attn + (long)z * Sn * Dn;

    f32x4 acc[4][4] = {};
    int srow = wv * 16 + (lane >> 2);
    int sch = (lane & 3) * 8;
    const u16* Ap = A + (m0 + srow) * 2048 + sch;
    const u16* Bp = B + (n0 + srow) * 2048 + sch;
    const int lofs = wv * 16 * 32;

    for (int k0 = 0; k0 < 2048; k0 += 64) {
      #pragma unroll
      for (int h = 0; h < 2; h++) {
        int kh = k0 + h * 32;
        gload_lds16(Ap + kh, &sA0[h * 128 * 32 + lofs]);
        gload_lds16(Ap + 64 * 2048 + kh, &sA0[h * 128 * 32 + lofs + 64 * 32]);
        gload_lds16(Bp + kh, &sB0[h * 128 * 32 + lofs]);
        gload_lds16(Bp + 64 * 2048 + kh, &sB0[h * 128 * 32 + lofs + 64 * 32]);
      }
      __syncthreads();
      #pragma unroll
      for (int h = 0; h < 2; h++) {
        bf16x8 af[4], bfr[4];
        #pragma unroll
        for (int mi = 0; mi < 4; mi++)
          af[mi] = *(const bf16x8*)&sA0[h * 128 * 32 + (wr * 64 + mi * 16 + lm) * 32 + quad * 8];
        #pragma unroll
        for (int ni = 0; ni < 4; ni++)
          bfr[ni] = *(const bf16x8*)&sB0[h * 128 * 32 + (wc * 64 + ni * 16 + lm) * 32 + quad * 8];
        #pragma unroll
        for (int mi = 0; mi < 4; mi++)
          #pragma unroll
          for (int ni = 0; ni < 4; ni++)
            acc[mi][ni] = __builtin_amdgcn_mfma_f32_16x16x32_bf16(af[mi], bfr[ni], acc[mi][ni], 0, 0, 0);
      }
      __syncthreads();
    }
    float inv[4][4];
    #pragma unroll
    for (int mi = 0; mi < 4; mi++)
      #pragma unroll
      for (int r = 0; r < 4; r++) {
        long rowg = m0 + wr * 64 + mi * 16 + quad * 4 + r;
        inv[mi][r] = 1.0f / rowsum[(long)z * 2048 + rowg];
      }
    #pragma unroll
    for (int mi = 0; mi < 4; mi++) {
      #pragma unroll
      for (int ni = 0; ni < 4; ni++) {
        int col = (int)n0 + wc * 64 + ni * 16 + lm;
        #pragma unroll
        for (int r = 0; r < 4; r++) {
          long rowg = m0 + wr * 64 + mi * 16 + quad * 4 + r;
          C[rowg * 1024 + col] = f2bf(acc[mi][ni][r] * inv[mi][r]);
        }
      }
    }
  } else {
    u16 (*sx)[72] = (u16(*)[72])smem;
    u16 (*sw)[200] = (u16(*)[200])(smem + 9360);
    int r = blk - npv;
    int s0 = (r & 15) * 128;
    int g = (r >> 4) & 15;
    int b = r >> 8;
    int lane = tid & 63, wv = tid >> 6;
    int quad = lane >> 4, lm = lane & 15;
    for (int idx = tid; idx < 64 * 192; idx += 256) {
      int oc = idx / 192, k = idx - oc * 192;
      int t2 = k >> 6, i = k & 63;
      sw[oc][k] = f2bf(cw[((long)(g * 64 + oc)) * 192 + i * 3 + t2]);
    }
    for (int idx = tid; idx < 130 * 16; idx += 256) {
      int rr = idx >> 4, c4 = (idx & 15) * 4;
      int s = s0 - 1 + rr;
      ushort4 v;
      if (s >= 0 && s < Sn) {
        float4 f = *(const float4*)&x[((long)b * Sn + s) * Dn + g * 64 + c4];
        v.x = f2bf(f.x); v.y = f2bf(f.y); v.z = f2bf(f.z); v.w = f2bf(f.w);
      } else { v.x = 0; v.y = 0; v.z = 0; v.w = 0; }
      *(ushort4*)&sx[rr][c4] = v;
    }
    __syncthreads();
    f32x4 acc[2][4] = {};
    #pragma unroll
    for (int ks = 0; ks < 6; ks++) {
      int t2 = ks >> 1;
      int i0 = (ks & 1) * 32 + quad * 8;
      bf16x8 a0 = *(const bf16x8*)&sx[wv * 32 + lm + t2][i0];
      bf16x8 a1 = *(const bf16x8*)&sx[wv * 32 + 16 + lm + t2][i0];
      #pragma unroll
      for (int nf = 0; nf < 4; nf++) {
        bf16x8 bf = *(const bf16x8*)&sw[nf * 16 + lm][ks * 32 + quad * 8];
        acc[0][nf] = __builtin_amdgcn_mfma_f32_16x16x32_bf16(a0, bf, acc[0][nf], 0, 0, 0);
        acc[1][nf] = __builtin_amdgcn_mfma_f32_16x16x32_bf16(a1, bf, acc[1][nf], 0, 0, 0);
      }
    }
    #pragma unroll
    for (int mi = 0; mi < 2; mi++) {
      #pragma unroll
      for (int nf = 0; nf < 4; nf++) {
        int col = g * 64 + nf * 16 + lm;
        float bias = cb[col];
        #pragma unroll
        for (int rr = 0; rr < 4; rr++) {
          int row = wv * 32 + mi * 16 + quad * 4 + rr;
          convo[((long)b * Sn + s0 + row) * Dn + col] = f2bf(acc[mi][nf][rr] + bias);
        }
      }
    }
  }
}

// ======== ln2: combined = LN2(LN1(conv) + attn), LN1 in f32, one pass ======
__global__ __launch_bounds__(256)
void ln2_kernel(const u16* __restrict__ conv, const u16* __restrict__ attn,
                const float* __restrict__ gamma, const float* __restrict__ beta,
                u16* __restrict__ out) {
  __shared__ float red[4];
  int tid = threadIdx.x;
  long base = (long)blockIdx.x * Dn + tid * 4;
  ushort4 cv = *(const ushort4*)&conv[base];
  float c0 = bf2f(cv.x), c1 = bf2f(cv.y), c2 = bf2f(cv.z), c3 = bf2f(cv.w);
  float4 gv = *(const float4*)&gamma[tid * 4];
  float4 bev = *(const float4*)&beta[tid * 4];
  float s1 = block_allreduce_sum(c0 + c1 + c2 + c3, red, tid);
  float mean1 = s1 * (1.0f / 1024.0f);
  float d0 = c0 - mean1, d1 = c1 - mean1, d2 = c2 - mean1, d3 = c3 - mean1;
  float sq1 = block_allreduce_sum(d0 * d0 + d1 * d1 + d2 * d2 + d3 * d3, red, tid);
  float inv1 = 1.0f / (sqrtf(sq1 * (1.0f / 1023.0f)) + 1e-6f);
  ushort4 av = *(const ushort4*)&attn[base];
  float v0 = gv.x * d0 * inv1 + bev.x + bf2f(av.x);
  float v1 = gv.y * d1 * inv1 + bev.y + bf2f(av.y);
  float v2 = gv.z * d2 * inv1 + bev.z + bf2f(av.z);
  float v3 = gv.w * d3 * inv1 + bev.w + bf2f(av.w);
  float s2 = block_allreduce_sum(v0 + v1 + v2 + v3, red, tid);
  float mean2 = s2 * (1.0f / 1024.0f);
  float e0 = v0 - mean2, e1 = v1 - mean2, e2 = v2 - mean2, e3 = v3 - mean2;
  float sq2 = block_allreduce_sum(e0 * e0 + e1 * e1 + e2 * e2 + e3 * e3, red, tid);
  float inv2 = 1.0f / (sqrtf(sq2 * (1.0f / 1023.0f)) + 1e-6f);
  ushort4 o;
  o.x = f2bf(gv.x * e0 * inv2 + bev.x);
  o.y = f2bf(gv.y * e1 * inv2 + bev.y);
  o.z = f2bf(gv.z * e2 * inv2 + bev.z);
  o.w = f2bf(gv.w * e3 * inv2 + bev.w);
  *(ushort4*)&out[base] = o;
}

// ================= workspace layout =================
static const size_t OFF_WT    = 0;
static const size_t OFF_QKVB  = 8ull << 20;
static const size_t OFF_WB    = (8ull << 20) + (12 << 10);
static const size_t OFF_RSUM  = (8ull << 20) + (16 << 10);
static const size_t OFF_KV    = (8ull << 20) + (48 << 10);
static const size_t OFF_Q     = 9ull << 20;
static const size_t OFF_K     = 25ull << 20;
static const size_t OFF_V     = 41ull << 20;
static const size_t OFF_PW    = 57ull << 20;

extern "C" void kernel_launch(void* const* d_in, const int* in_sizes, int n_in,
                              void* d_out, int out_size, void* d_ws, size_t ws_size,
                              hipStream_t stream) {
  const float* x     = (const float*)d_in[0];
  const float* Wq    = (const float*)d_in[1];
  const float* bq    = (const float*)d_in[2];
  const float* Wk    = (const float*)d_in[3];
  const float* Wv    = (const float*)d_in[4];
  const float* bv    = (const float*)d_in[5];
  const float* cw    = (const float*)d_in[6];
  const float* cb    = (const float*)d_in[7];
  const float* gamma = (const float*)d_in[8];
  const float* beta  = (const float*)d_in[9];
  const float* Wo    = (const float*)d_in[10];
  const float* bo    = (const float*)d_in[11];
  float* out = (float*)d_out;
  char* ws = (char*)d_ws;

  u16*   wT    = (u16*)(ws + OFF_WT);
  float* qkvb  = (float*)(ws + OFF_QKVB);
  float* wb    = (float*)(ws + OFF_WB);
  float* rsum  = (float*)(ws + OFF_RSUM);
  float* kv    = (float*)(ws + OFF_KV);
  u16*   Qb    = (u16*)(ws + OFF_Q);
  u16*   Kb    = (u16*)(ws + OFF_K);
  u16*   Vb    = (u16*)(ws + OFF_V);
  u16*   Pw    = (u16*)(ws + OFF_PW);
  u16*   wqo   = Pw;                        // bf16 Wq orig-layout (early use)
  u16*   wko   = Pw + 1048576;              // bf16 Wk orig-layout
  u16*   xb    = (u16*)d_out;               // bf16 x; live until scores done
  u16*   vt    = (u16*)d_out + 8388608;     // V^T [4][1024][2048]
  u16*   conv  = Vb;
  u16*   attn  = Qb;                        // overwrites xq' after scores
  u16*   combined = Kb;                     // overwrites P b0,1 after PV
  const long PBS = (long)Sn * Sn;

  dim3 tb(256);

  if (ws_size >= (73ull << 20)) {
    // 1. prologue: wT + bias + rsum0 + xb + Wq_o/Wk_o + wb
    prep_all<<<dim3(11281), tb, 0, stream>>>(Wq, Wk, Wv, Wo, wT, bq, bv, qkvb,
                                             rsum, x, xb, wqo, wko, wb);
    // 2. V->vt (transposed) + G = Wk.Wq^T (into wT slot 0) + kv riders
    vg_kv<<<dim3(640), tb, 0, stream>>>(xb, wT + 2u * 1048576u, wqo, wko,
                                        qkvb + 2048, vt, wT, wb, kv);
    // 3. xq' = xb . G^T  -> Qb
    gemm_nt<u16><<<dim3(64, 8, 1), tb, 0, stream>>>(
        xb, nullptr, 0, 1024, wT, 0, 1024, Qb, (u16*)nullptr, 0, 1024,
        99, 1024, 1.0f, nullptr, 0, nullptr, 0, 0, nullptr);
    // 4. scores = xq'.xb^T + kv (exp + rowsum epilogue); P b0,1 -> Kb
    post_qkv<<<dim3(1024), tb, 0, stream>>>(1024, Qb, xb, Kb, Pw, Vb, vt,
                                            rsum, kv);
    // 5. PV (normalize) + conv riders -> Vb
    pv_conv<<<dim3(512 + 1024), tb, 0, stream>>>(512, Kb, Pw, vt, attn, rsum,
                                                 x, cw, cb, conv);
    // 6. combined = LN2(LN1(conv) + attn) -> Kb
    ln2_kernel<<<dim3(8192), tb, 0, stream>>>(conv, attn, gamma, beta, combined);
  } else {
    // fallback: classic flow (Q,K,V planes; V^T riders; classic softmax)
    prep_all<<<dim3(11281), tb, 0, stream>>>(Wq, Wk, Wv, Wo, wT, bq, bv, qkvb,
                                             rsum, x, xb, wqo, wko, wb);
    u16* Pd = (u16*)d_out;
    gemm_nt<u16><<<dim3(64, 8, 3), tb, 0, stream>>>(
        xb, nullptr, 0, 1024, wT, 1048576, 1024, Qb, (u16*)nullptr, 8388608, 1024,
        99, 1024, 1.0f, qkvb, 1024, nullptr, 0, 0, nullptr);
    post_qkv<<<dim3(2048), tb, 0, stream>>>(0, Qb, Kb, Pd, Pw, Vb, vt, rsum,
                                            nullptr);
    for (int c = 0; c < 2; c++) {
      long off = (long)c * 2 * Sn * Dn;
      gemm_nt<u16><<<dim3(16, 16, 2), tb, 0, stream>>>(
          Qb + off, nullptr, (long)Sn * Dn, 1024, Kb + off, (long)Sn * Dn, 1024,
          Pd, (u16*)nullptr, PBS, 2048,
          99, 1024, 0.03125f, nullptr, 0, nullptr, 0, 0, nullptr);
      smax_conv<<<dim3(4096 + (c == 0 ? 1024 : 0)), tb, 0, stream>>>(
          Pd, Pd, 4096, 4096, x, cw, cb, conv);
      gemm_nt<u16><<<dim3(16, 8, 2), tb, 0, stream>>>(
          Pd, nullptr, PBS, 2048, vt + off, (long)Dn * Sn, 2048,
          attn + off, (u16*)nullptr, (long)Sn * Dn, 1024,
          99, 2048, 1.0f, nullptr, 0, nullptr, 0, 0, nullptr);
    }
    ln2_kernel<<<dim3(8192), tb, 0, stream>>>(conv, attn, gamma, beta, combined);
  }

  // 7. out = combined @ Wo + bo + x
  gemm_nt<float><<<dim3(64, 8, 1), tb, 0, stream>>>(
      combined, nullptr, 0, 1024, wT + 3u * 1048576u, 0, 1024,
      out, (float*)nullptr, 0, 1024,
      99, 1024, 1.0f, bo, 0, x, 0, 1024, nullptr);
}

// Round 8
// 331.891 us; speedup vs baseline: 1.0383x; 1.0383x over previous
//
#include <hip/hip_runtime.h>
#include <cstdint>

// DynamicConvAttention: B=4, S=2048, D=1024, NH=16 (groups), K=3
// f32 I/O, bf16 MFMA internal. 6 launches (primary path).
//
// ws (73 MB primary path):
//   wT   [0, 8 MB)      bf16 WqT,WkT,WvT,WoT (1M u16 each)
//   qkvb [8 MB, +12 KB) f32 concat bias [bq|0|bv]
//   rsum [8 MB+16KB, +32KB) f32 softmax row sums [8192]
//   Q    [9, 25 MB)  bf16 [8192][1024]  (attn overwrites after scores)
//   K    [25, 41 MB) bf16               (combined after scores)
//   V    [41, 57 MB) bf16  unused by primary QKV -> conv output buffer
//   Pw   [57, 73 MB) bf16 P batches 2,3 (4096 rows)
// d_out (33.5 MB f32) as scratch:
//   xb = d_out[0:16.78MB)    bf16 x (dead after QKV) -> then P batches 0,1
//   vt = d_out[+8388608 u16] bf16 V^T [4][1024][2048] (dead after PV)
//
// r16: REVERTED r15 K-fold (344.6 us, worse: prep growth + extra launch
// boundary outweighed the deleted K-plane). Back to r14 (329.4 us) with
// ONE change: conv riders moved from the PV launch to the SCORES launch
// (conv depends only on x). pv launch becomes 512 blocks = exactly 1
// clean round; scores launch's ragged tails absorb the 1024 light conv
// blocks. r13/r14 kept: unnormalized-exp softmax (P'=exp(s/32), f32
// rowsum atomics, normalize in PV epilogue); V written TRANSPOSED into
// vt directly by the QKV z=2 epilogue.

#define DEV __device__ __forceinline__

typedef unsigned short u16;
typedef __attribute__((ext_vector_type(8))) short bf16x8;
typedef __attribute__((ext_vector_type(4))) float f32x4;

static const int Sn = 2048, Dn = 1024;

DEV float bf2f(u16 u) { union { unsigned int i; float f; } w; w.i = ((unsigned int)u) << 16; return w.f; }
DEV u16 f2bf(float f) {
  union { float f; unsigned int i; } w; w.f = f;
  unsigned int x = w.i;
  return (u16)((x + 0x7FFFu + ((x >> 16) & 1u)) >> 16);
}

DEV void gload_lds16(const u16* gsrc, u16* lds_dst) {
  __builtin_amdgcn_global_load_lds(
      (const __attribute__((address_space(1))) void*)gsrc,
      (__attribute__((address_space(3))) void*)lds_dst,
      16, 0, 0);
}

DEV float block_allreduce_sum(float v, float* red, int tid) {
  #pragma unroll
  for (int o = 32; o > 0; o >>= 1) v += __shfl_down(v, o, 64);
  __syncthreads();
  if ((tid & 63) == 0) red[tid >> 6] = v;
  __syncthreads();
  return red[0] + red[1] + red[2] + red[3];
}

DEV float block_allreduce_max(float v, float* red, int tid) {
  #pragma unroll
  for (int o = 32; o > 0; o >>= 1) v = fmaxf(v, __shfl_down(v, o, 64));
  __syncthreads();
  if ((tid & 63) == 0) red[tid >> 6] = v;
  __syncthreads();
  return fmaxf(fmaxf(red[0], red[1]), fmaxf(red[2], red[3]));
}

// ---- grouped conv body (shared by post_qkv riders and fallback) ----
// out[s,oc] = cb[oc] + sum_k x[s+t-1, g*64+i]*w[oc, k=t*64+i]
DEV void conv_body(u16* smem, int r, int tid,
                   const float* __restrict__ x, const float* __restrict__ cw,
                   const float* __restrict__ cb, u16* __restrict__ convo) {
  u16 (*sx)[72] = (u16(*)[72])smem;
  u16 (*sw)[200] = (u16(*)[200])(smem + 9360);
  int s0 = (r & 15) * 128;
  int g = (r >> 4) & 15;
  int b = r >> 8;
  int lane = tid & 63, wv = tid >> 6;
  int quad = lane >> 4, lm = lane & 15;
  for (int idx = tid; idx < 64 * 192; idx += 256) {
    int oc = idx / 192, k = idx - oc * 192;
    int t2 = k >> 6, i = k & 63;
    sw[oc][k] = f2bf(cw[((long)(g * 64 + oc)) * 192 + i * 3 + t2]);
  }
  for (int idx = tid; idx < 130 * 16; idx += 256) {
    int rr = idx >> 4, c4 = (idx & 15) * 4;
    int s = s0 - 1 + rr;
    ushort4 v;
    if (s >= 0 && s < Sn) {
      float4 f = *(const float4*)&x[((long)b * Sn + s) * Dn + g * 64 + c4];
      v.x = f2bf(f.x); v.y = f2bf(f.y); v.z = f2bf(f.z); v.w = f2bf(f.w);
    } else { v.x = 0; v.y = 0; v.z = 0; v.w = 0; }
    *(ushort4*)&sx[rr][c4] = v;
  }
  __syncthreads();
  f32x4 acc[2][4] = {};
  #pragma unroll
  for (int ks = 0; ks < 6; ks++) {
    int t2 = ks >> 1;
    int i0 = (ks & 1) * 32 + quad * 8;
    bf16x8 a0 = *(const bf16x8*)&sx[wv * 32 + lm + t2][i0];
    bf16x8 a1 = *(const bf16x8*)&sx[wv * 32 + 16 + lm + t2][i0];
    #pragma unroll
    for (int nf = 0; nf < 4; nf++) {
      bf16x8 bf = *(const bf16x8*)&sw[nf * 16 + lm][ks * 32 + quad * 8];
      acc[0][nf] = __builtin_amdgcn_mfma_f32_16x16x32_bf16(a0, bf, acc[0][nf], 0, 0, 0);
      acc[1][nf] = __builtin_amdgcn_mfma_f32_16x16x32_bf16(a1, bf, acc[1][nf], 0, 0, 0);
    }
  }
  #pragma unroll
  for (int mi = 0; mi < 2; mi++) {
    #pragma unroll
    for (int nf = 0; nf < 4; nf++) {
      int col = g * 64 + nf * 16 + lm;
      float bias = cb[col];
      #pragma unroll
      for (int rr = 0; rr < 4; rr++) {
        int row = wv * 32 + mi * 16 + quad * 4 + rr;
        convo[((long)b * Sn + s0 + row) * Dn + col] = f2bf(acc[mi][nf][rr] + bias);
      }
    }
  }
}

// ================= prep_all: weights T + bias + rowsum zero + x cvt ========
__global__ __launch_bounds__(256)
void prep_all(const float* __restrict__ Wq, const float* __restrict__ Wk,
              const float* __restrict__ Wv, const float* __restrict__ Wo,
              u16* __restrict__ wT,
              const float* __restrict__ bq, const float* __restrict__ bv,
              float* __restrict__ qkvb, float* __restrict__ rowsum,
              const float* __restrict__ x, u16* __restrict__ xb) {
  __shared__ u16 sm[64][68];
  int blk = blockIdx.x;
  int tid = threadIdx.x;
  if (blk < 1024) {
    int w = blk >> 8, t = blk & 255;
    const float* src = (w == 0) ? Wq : (w == 1) ? Wk : (w == 2) ? Wv : Wo;
    u16* dst = wT + (size_t)w * 1048576u;
    int i0 = (t >> 4) << 6, j0 = (t & 15) << 6;
    int tx = tid & 15, r0 = tid >> 4;
    #pragma unroll
    for (int rr = r0; rr < 64; rr += 16) {
      float4 v = *(const float4*)&src[(long)(i0 + rr) * 1024 + j0 + tx * 4];
      sm[rr][tx*4+0] = f2bf(v.x); sm[rr][tx*4+1] = f2bf(v.y);
      sm[rr][tx*4+2] = f2bf(v.z); sm[rr][tx*4+3] = f2bf(v.w);
    }
    __syncthreads();
    #pragma unroll
    for (int cc = r0; cc < 64; cc += 16) {
      ushort4 o;
      o.x = sm[tx*4+0][cc]; o.y = sm[tx*4+1][cc];
      o.z = sm[tx*4+2][cc]; o.w = sm[tx*4+3][cc];
      *(ushort4*)&dst[(long)(j0 + cc) * 1024 + i0 + tx * 4] = o;
    }
  } else if (blk == 1024) {
    for (int j = tid; j < 3072; j += 256) {
      float v = 0.0f;
      if (j < 1024) v = bq[j];
      else if (j >= 2048) v = bv[j - 2048];
      qkvb[j] = v;
    }
    for (int j = tid; j < 8192; j += 256) rowsum[j] = 0.0f;
  } else {
    int i = (blk - 1025) * 1024 + tid * 4;
    float4 v = *(const float4*)&x[i];
    ushort4 o;
    o.x = f2bf(v.x); o.y = f2bf(v.y); o.z = f2bf(v.z); o.w = f2bf(v.w);
    *(ushort4*)&xb[i] = o;
  }
}

// ================= NT GEMM, BK=64 split-halves (proven r7 core) ============
// vtout: if non-null and z==2 (bf16 out), epilogue writes tile TRANSPOSED
// into vtout[b][d][s] (b = m0>>11, d = col, s = row&2047).
template<typename CT>
__global__ __launch_bounds__(256, 2)
void gemm_nt(const u16* __restrict__ A, const u16* __restrict__ A2, long Abs, int lda,
             const u16* __restrict__ B, long Bbs, int ldb,
             CT* __restrict__ C, CT* __restrict__ C2, long Cbs, int ldc,
             int zsplit, int K, float scale,
             const float* __restrict__ bias, int bias_bs,
             const float* __restrict__ res, long Rbs, int ldr,
             u16* __restrict__ vtout) {
  __shared__ u16 sA[2][128 * 32];
  __shared__ u16 sB[2][128 * 32];
  int tid = threadIdx.x;
  int lane = tid & 63, wv = tid >> 6;
  int quad = lane >> 4, lm = lane & 15;
  int wr = wv >> 1, wc = wv & 1;
  long m0 = (long)blockIdx.x * 128, n0 = (long)blockIdx.y * 128;
  int z = blockIdx.z;
  if (z >= zsplit) { A = A2 + (long)(z - zsplit) * Abs; C = C2 + (long)(z - zsplit) * Cbs; }
  else             { A = A  + (long)z * Abs;            C = C  + (long)z * Cbs; }
  B += (long)z * Bbs;
  if (res) res += (long)z * Rbs;

  f32x4 acc[4][4] = {};

  int srow = wv * 16 + (lane >> 2);
  int sch = (lane & 3) * 8;
  const u16* Ap = A + (m0 + srow) * (long)lda + sch;
  const u16* Bp = B + (n0 + srow) * (long)ldb + sch;
  const int lofs = wv * 16 * 32;

  for (int k0 = 0; k0 < K; k0 += 64) {
    #pragma unroll
    for (int h = 0; h < 2; h++) {
      int kh = k0 + h * 32;
      gload_lds16(Ap + kh, &sA[h][lofs]);
      gload_lds16(Ap + 64 * (long)lda + kh, &sA[h][lofs + 64 * 32]);
      gload_lds16(Bp + kh, &sB[h][lofs]);
      gload_lds16(Bp + 64 * (long)ldb + kh, &sB[h][lofs + 64 * 32]);
    }
    __syncthreads();
    #pragma unroll
    for (int h = 0; h < 2; h++) {
      bf16x8 af[4], bfr[4];
      #pragma unroll
      for (int mi = 0; mi < 4; mi++)
        af[mi] = *(const bf16x8*)&sA[h][(wr * 64 + mi * 16 + lm) * 32 + quad * 8];
      #pragma unroll
      for (int ni = 0; ni < 4; ni++)
        bfr[ni] = *(const bf16x8*)&sB[h][(wc * 64 + ni * 16 + lm) * 32 + quad * 8];
      #pragma unroll
      for (int mi = 0; mi < 4; mi++)
        #pragma unroll
        for (int ni = 0; ni < 4; ni++)
          acc[mi][ni] = __builtin_amdgcn_mfma_f32_16x16x32_bf16(af[mi], bfr[ni], acc[mi][ni], 0, 0, 0);
    }
    __syncthreads();
  }

  if (sizeof(CT) == 2 && vtout && z == 2) {
    int b = (int)(m0 >> 11);
    long s0 = (m0 & 2047) + wr * 64 + quad * 4;
    #pragma unroll
    for (int ni = 0; ni < 4; ni++) {
      int col = (int)n0 + wc * 64 + ni * 16 + lm;
      float bv = bias ? bias[(long)z * bias_bs + col] : 0.0f;
      u16* vrow = vtout + ((long)b * 1024 + col) * 2048;
      #pragma unroll
      for (int mi = 0; mi < 4; mi++) {
        ushort4 o;
        o.x = f2bf(acc[mi][ni][0] * scale + bv);
        o.y = f2bf(acc[mi][ni][1] * scale + bv);
        o.z = f2bf(acc[mi][ni][2] * scale + bv);
        o.w = f2bf(acc[mi][ni][3] * scale + bv);
        *(ushort4*)&vrow[s0 + mi * 16] = o;
      }
    }
  } else {
    #pragma unroll
    for (int mi = 0; mi < 4; mi++) {
      #pragma unroll
      for (int ni = 0; ni < 4; ni++) {
        int col = (int)n0 + wc * 64 + ni * 16 + lm;
        float bv = bias ? bias[(long)z * bias_bs + col] : 0.0f;
        #pragma unroll
        for (int r = 0; r < 4; r++) {
          long rowg = m0 + wr * 64 + mi * 16 + quad * 4 + r;
          float v = acc[mi][ni][r] * scale + bv;
          if (res) v += res[rowg * (long)ldr + col];
          if constexpr (sizeof(CT) == 2) C[rowg * (long)ldc + col] = f2bf(v);
          else                           C[rowg * (long)ldc + col] = v;
        }
      }
    }
  }
}

// ====== post_qkv: scores GEMM (exp + rowsum) + conv riders [+V^T fb] ======
// blocks [0, ngemm)             : scores tile; epilogue P'=exp(s/32),
//                                 rowsum via shfl-reduce + atomic
// blocks [ngemm, ngemm+nconv)   : grouped conv -> convo (reads x only)
// blocks [ngemm+nconv, ...)     : V^T 64x64 tiles (FALLBACK PATH ONLY)
__global__ __launch_bounds__(256, 2)
void post_qkv(int ngemm, int nconv,
              const u16* __restrict__ Qb, const u16* __restrict__ Kb,
              u16* __restrict__ Pd, u16* __restrict__ Pw,
              const u16* __restrict__ Vb, u16* __restrict__ vt,
              float* __restrict__ rowsum,
              const float* __restrict__ x, const float* __restrict__ cw,
              const float* __restrict__ cb, u16* __restrict__ convo) {
  __shared__ u16 smem[22160];  // scores uses first 16384 u16; conv uses 22160
  int blk = blockIdx.x;
  int tid = threadIdx.x;
  if (blk < ngemm) {
    u16* sA0 = smem;
    u16* sB0 = smem + 2 * 128 * 32;
    int lane = tid & 63, wv = tid >> 6;
    int quad = lane >> 4, lm = lane & 15;
    int wr = wv >> 1, wc = wv & 1;
    int z = blk >> 8;
    long m0 = (long)(blk & 15) * 128, n0 = (long)((blk >> 4) & 15) * 128;
    const u16* A = Qb + (long)z * Sn * Dn;
    const u16* B = Kb + (long)z * Sn * Dn;
    u16* C = (z < 2) ? Pd + (long)z * Sn * Sn : Pw + (long)(z - 2) * Sn * Sn;

    f32x4 acc[4][4] = {};
    int srow = wv * 16 + (lane >> 2);
    int sch = (lane & 3) * 8;
    const u16* Ap = A + (m0 + srow) * 1024 + sch;
    const u16* Bp = B + (n0 + srow) * 1024 + sch;
    const int lofs = wv * 16 * 32;

    for (int k0 = 0; k0 < 1024; k0 += 64) {
      #pragma unroll
      for (int h = 0; h < 2; h++) {
        int kh = k0 + h * 32;
        gload_lds16(Ap + kh, &sA0[h * 128 * 32 + lofs]);
        gload_lds16(Ap + 64 * 1024 + kh, &sA0[h * 128 * 32 + lofs + 64 * 32]);
        gload_lds16(Bp + kh, &sB0[h * 128 * 32 + lofs]);
        gload_lds16(Bp + 64 * 1024 + kh, &sB0[h * 128 * 32 + lofs + 64 * 32]);
      }
      __syncthreads();
      #pragma unroll
      for (int h = 0; h < 2; h++) {
        bf16x8 af[4], bfr[4];
        #pragma unroll
        for (int mi = 0; mi < 4; mi++)
          af[mi] = *(const bf16x8*)&sA0[h * 128 * 32 + (wr * 64 + mi * 16 + lm) * 32 + quad * 8];
        #pragma unroll
        for (int ni = 0; ni < 4; ni++)
          bfr[ni] = *(const bf16x8*)&sB0[h * 128 * 32 + (wc * 64 + ni * 16 + lm) * 32 + quad * 8];
        #pragma unroll
        for (int mi = 0; mi < 4; mi++)
          #pragma unroll
          for (int ni = 0; ni < 4; ni++)
            acc[mi][ni] = __builtin_amdgcn_mfma_f32_16x16x32_bf16(af[mi], bfr[ni], acc[mi][ni], 0, 0, 0);
      }
      __syncthreads();
    }
    // epilogue: P' = exp(s/32); per-row partial sums -> shfl reduce over lm
    float psum[4][4];
    #pragma unroll
    for (int mi = 0; mi < 4; mi++)
      #pragma unroll
      for (int r = 0; r < 4; r++) psum[mi][r] = 0.0f;
    #pragma unroll
    for (int mi = 0; mi < 4; mi++) {
      #pragma unroll
      for (int ni = 0; ni < 4; ni++) {
        int col = (int)n0 + wc * 64 + ni * 16 + lm;
        #pragma unroll
        for (int r = 0; r < 4; r++) {
          long rowg = m0 + wr * 64 + mi * 16 + quad * 4 + r;
          float e = __expf(acc[mi][ni][r] * 0.03125f);
          psum[mi][r] += e;
          C[rowg * 2048 + col] = f2bf(e);
        }
      }
    }
    #pragma unroll
    for (int mi = 0; mi < 4; mi++)
      #pragma unroll
      for (int r = 0; r < 4; r++) {
        float v = psum[mi][r];
        v += __shfl_xor(v, 1, 64);
        v += __shfl_xor(v, 2, 64);
        v += __shfl_xor(v, 4, 64);
        v += __shfl_xor(v, 8, 64);
        psum[mi][r] = v;
      }
    if (lm == 0) {
      #pragma unroll
      for (int mi = 0; mi < 4; mi++)
        #pragma unroll
        for (int r = 0; r < 4; r++) {
          long rowg = m0 + wr * 64 + mi * 16 + quad * 4 + r;
          unsafeAtomicAdd(&rowsum[(long)z * 2048 + rowg], psum[mi][r]);
        }
    }
  } else if (blk < ngemm + nconv) {
    conv_body(smem, blk - ngemm, tid, x, cw, cb, convo);
  } else {
    u16 (*sm)[68] = (u16(*)[68])smem;
    int t = blk - ngemm - nconv;
    int b = t >> 9, r = t & 511;
    int j0 = (r & 15) << 6, i0 = ((r >> 4) & 31) << 6;
    const u16* s = Vb + (long)b * Sn * Dn;
    u16* d = vt + (long)b * Dn * Sn;
    int tx = tid & 15, r0 = tid >> 4;
    #pragma unroll
    for (int rr = r0; rr < 64; rr += 16) {
      ushort4 v = *(const ushort4*)&s[(long)(i0 + rr) * 1024 + j0 + tx * 4];
      sm[rr][tx*4+0] = v.x; sm[rr][tx*4+1] = v.y; sm[rr][tx*4+2] = v.z; sm[rr][tx*4+3] = v.w;
    }
    __syncthreads();
    #pragma unroll
    for (int cc = r0; cc < 64; cc += 16) {
      ushort4 o;
      o.x = sm[tx*4+0][cc]; o.y = sm[tx*4+1][cc];
      o.z = sm[tx*4+2][cc]; o.w = sm[tx*4+3][cc];
      *(ushort4*)&d[(long)(j0 + cc) * 2048 + i0 + tx * 4] = o;
    }
  }
}

// ==== smax_conv: kept for fallback (softmax rows + grouped conv) ===========
__global__ __launch_bounds__(256)
void smax_conv(u16* __restrict__ pa, u16* __restrict__ pb, int rowsplit, int nsm,
               const float* __restrict__ x, const float* __restrict__ cw,
               const float* __restrict__ cb, u16* __restrict__ convo) {
  __shared__ u16 smem[22160];
  __shared__ float red[4];
  int blk = blockIdx.x;
  int tid = threadIdx.x;
  if (blk < nsm) {
    long row = blk;
    u16* p = (row < rowsplit) ? pa + row * 2048 : pb + (row - rowsplit) * 2048;
    ushort4 a = *(const ushort4*)&p[tid * 8];
    ushort4 b = *(const ushort4*)&p[tid * 8 + 4];
    float f0 = bf2f(a.x), f1 = bf2f(a.y), f2 = bf2f(a.z), f3 = bf2f(a.w);
    float f4 = bf2f(b.x), f5 = bf2f(b.y), f6 = bf2f(b.z), f7 = bf2f(b.w);
    float m = fmaxf(fmaxf(fmaxf(f0, f1), fmaxf(f2, f3)),
                    fmaxf(fmaxf(f4, f5), fmaxf(f6, f7)));
    m = block_allreduce_max(m, red, tid);
    float e0 = __expf(f0 - m), e1 = __expf(f1 - m), e2 = __expf(f2 - m), e3 = __expf(f3 - m);
    float e4 = __expf(f4 - m), e5 = __expf(f5 - m), e6 = __expf(f6 - m), e7 = __expf(f7 - m);
    float s = block_allreduce_sum(e0 + e1 + e2 + e3 + e4 + e5 + e6 + e7, red, tid);
    float inv = 1.0f / s;
    ushort4 o1, o2;
    o1.x = f2bf(e0 * inv); o1.y = f2bf(e1 * inv); o1.z = f2bf(e2 * inv); o1.w = f2bf(e3 * inv);
    o2.x = f2bf(e4 * inv); o2.y = f2bf(e5 * inv); o2.z = f2bf(e6 * inv); o2.w = f2bf(e7 * inv);
    *(ushort4*)&p[tid * 8] = o1;
    *(ushort4*)&p[tid * 8 + 4] = o2;
  } else {
    conv_body(smem, blk - nsm, tid, x, cw, cb, convo);
  }
}

// ============ pv_conv: PV GEMM (normalize epilogue) [+ conv riders] ========
// blocks [0, npv)        : PV tile (bx=r&15, by=(r>>4)&7, z=r>>7); K=2048
//                          epilogue: C = (P'V) * (1/rowsum[row])
// blocks [npv, ...)      : conv riders (unused in primary; grid == npv)
__global__ __launch_bounds__(256, 2)
void pv_conv(int npv,
             const u16* __restrict__ Pd, const u16* __restrict__ Pw,
             const u16* __restrict__ vt, u16* __restrict__ attn,
             const float* __restrict__ rowsum,
             const float* __restrict__ x, const float* __restrict__ cw,
             const float* __restrict__ cb, u16* __restrict__ convo) {
  __shared__ u16 smem[22160];
  int blk = blockIdx.x;
  int tid = threadIdx.x;
  if (blk < npv) {
    u16* sA0 = smem;
    u16* sB0 = smem + 2 * 128 * 32;
    int lane = tid & 63, wv = tid >> 6;
    int quad = lane >> 4, lm = lane & 15;
    int wr = wv >> 1, wc = wv & 1;
    int z = blk >> 7;
    long m0 = (long)(blk & 15) * 128, n0 = (long)((blk >> 4) & 7) * 128;
    const u16* A = (z < 2) ? Pd + (long)z * Sn * Sn : Pw + (long)(z - 2) * Sn * Sn;
    const u16* B = vt + (long)z * Dn * Sn;
    u16* C = attn + (long)z * Sn * Dn;

    f32x4 acc[4][4] = {};
    int srow = wv * 16 + (lane >> 2);
    int sch = (lane & 3) * 8;
    const u16* Ap = A + (m0 + srow) * 2048 + sch;
    const u16* Bp = B + (n0 + srow) * 2048 + sch;
    const int lofs = wv * 16 * 32;

    for (int k0 = 0; k0 < 2048; k0 += 64) {
      #pragma unroll
      for (int h = 0; h < 2; h++) {
        int kh = k0 + h * 32;
        gload_lds16(Ap + kh, &sA0[h * 128 * 32 + lofs]);
        gload_lds16(Ap + 64 * 2048 + kh, &sA0[h * 128 * 32 + lofs + 64 * 32]);
        gload_lds16(Bp + kh, &sB0[h * 128 * 32 + lofs]);
        gload_lds16(Bp + 64 * 2048 + kh, &sB0[h * 128 * 32 + lofs + 64 * 32]);
      }
      __syncthreads();
      #pragma unroll
      for (int h = 0; h < 2; h++) {
        bf16x8 af[4], bfr[4];
        #pragma unroll
        for (int mi = 0; mi < 4; mi++)
          af[mi] = *(const bf16x8*)&sA0[h * 128 * 32 + (wr * 64 + mi * 16 + lm) * 32 + quad * 8];
        #pragma unroll
        for (int ni = 0; ni < 4; ni++)
          bfr[ni] = *(const bf16x8*)&sB0[h * 128 * 32 + (wc * 64 + ni * 16 + lm) * 32 + quad * 8];
        #pragma unroll
        for (int mi = 0; mi < 4; mi++)
          #pragma unroll
          for (int ni = 0; ni < 4; ni++)
            acc[mi][ni] = __builtin_amdgcn_mfma_f32_16x16x32_bf16(af[mi], bfr[ni], acc[mi][ni], 0, 0, 0);
      }
      __syncthreads();
    }
    float inv[4][4];
    #pragma unroll
    for (int mi = 0; mi < 4; mi++)
      #pragma unroll
      for (int r = 0; r < 4; r++) {
        long rowg = m0 + wr * 64 + mi * 16 + quad * 4 + r;
        inv[mi][r] = 1.0f / rowsum[(long)z * 2048 + rowg];
      }
    #pragma unroll
    for (int mi = 0; mi < 4; mi++) {
      #pragma unroll
      for (int ni = 0; ni < 4; ni++) {
        int col = (int)n0 + wc * 64 + ni * 16 + lm;
        #pragma unroll
        for (int r = 0; r < 4; r++) {
          long rowg = m0 + wr * 64 + mi * 16 + quad * 4 + r;
          C[rowg * 1024 + col] = f2bf(acc[mi][ni][r] * inv[mi][r]);
        }
      }
    }
  } else {
    conv_body(smem, blk - npv, tid, x, cw, cb, convo);
  }
}

// ======== ln2: combined = LN2(LN1(conv) + attn), LN1 in f32, one pass ======
__global__ __launch_bounds__(256)
void ln2_kernel(const u16* __restrict__ conv, const u16* __restrict__ attn,
                const float* __restrict__ gamma, const float* __restrict__ beta,
                u16* __restrict__ out) {
  __shared__ float red[4];
  int tid = threadIdx.x;
  long base = (long)blockIdx.x * Dn + tid * 4;
  ushort4 cv = *(const ushort4*)&conv[base];
  float c0 = bf2f(cv.x), c1 = bf2f(cv.y), c2 = bf2f(cv.z), c3 = bf2f(cv.w);
  float4 gv = *(const float4*)&gamma[tid * 4];
  float4 bev = *(const float4*)&beta[tid * 4];
  float s1 = block_allreduce_sum(c0 + c1 + c2 + c3, red, tid);
  float mean1 = s1 * (1.0f / 1024.0f);
  float d0 = c0 - mean1, d1 = c1 - mean1, d2 = c2 - mean1, d3 = c3 - mean1;
  float sq1 = block_allreduce_sum(d0 * d0 + d1 * d1 + d2 * d2 + d3 * d3, red, tid);
  float inv1 = 1.0f / (sqrtf(sq1 * (1.0f / 1023.0f)) + 1e-6f);
  ushort4 av = *(const ushort4*)&attn[base];
  float v0 = gv.x * d0 * inv1 + bev.x + bf2f(av.x);
  float v1 = gv.y * d1 * inv1 + bev.y + bf2f(av.y);
  float v2 = gv.z * d2 * inv1 + bev.z + bf2f(av.z);
  float v3 = gv.w * d3 * inv1 + bev.w + bf2f(av.w);
  float s2 = block_allreduce_sum(v0 + v1 + v2 + v3, red, tid);
  float mean2 = s2 * (1.0f / 1024.0f);
  float e0 = v0 - mean2, e1 = v1 - mean2, e2 = v2 - mean2, e3 = v3 - mean2;
  float sq2 = block_allreduce_sum(e0 * e0 + e1 * e1 + e2 * e2 + e3 * e3, red, tid);
  float inv2 = 1.0f / (sqrtf(sq2 * (1.0f / 1023.0f)) + 1e-6f);
  ushort4 o;
  o.x = f2bf(gv.x * e0 * inv2 + bev.x);
  o.y = f2bf(gv.y * e1 * inv2 + bev.y);
  o.z = f2bf(gv.z * e2 * inv2 + bev.z);
  o.w = f2bf(gv.w * e3 * inv2 + bev.w);
  *(ushort4*)&out[base] = o;
}

// ================= workspace layout =================
static const size_t OFF_WT    = 0;
static const size_t OFF_QKVB  = 8ull << 20;
static const size_t OFF_RSUM  = (8ull << 20) + (16 << 10);
static const size_t OFF_Q     = 9ull << 20;
static const size_t OFF_K     = 25ull << 20;
static const size_t OFF_V     = 41ull << 20;
static const size_t OFF_PW    = 57ull << 20;

extern "C" void kernel_launch(void* const* d_in, const int* in_sizes, int n_in,
                              void* d_out, int out_size, void* d_ws, size_t ws_size,
                              hipStream_t stream) {
  const float* x     = (const float*)d_in[0];
  const float* Wq    = (const float*)d_in[1];
  const float* bq    = (const float*)d_in[2];
  const float* Wk    = (const float*)d_in[3];
  const float* Wv    = (const float*)d_in[4];
  const float* bv    = (const float*)d_in[5];
  const float* cw    = (const float*)d_in[6];
  const float* cb    = (const float*)d_in[7];
  const float* gamma = (const float*)d_in[8];
  const float* beta  = (const float*)d_in[9];
  const float* Wo    = (const float*)d_in[10];
  const float* bo    = (const float*)d_in[11];
  float* out = (float*)d_out;
  char* ws = (char*)d_ws;

  u16*   wT    = (u16*)(ws + OFF_WT);
  float* qkvb  = (float*)(ws + OFF_QKVB);
  float* rsum  = (float*)(ws + OFF_RSUM);
  u16*   Qb    = (u16*)(ws + OFF_Q);
  u16*   Kb    = (u16*)(ws + OFF_K);
  u16*   Vb    = (u16*)(ws + OFF_V);
  u16*   Pw    = (u16*)(ws + OFF_PW);
  u16*   xb    = (u16*)d_out;               // dead after QKV; then P b0,1
  u16*   Pd    = (u16*)d_out;
  u16*   vt    = (u16*)d_out + 8388608;     // V^T, dead after PV
  u16*   conv  = Vb;                        // conv output (Vb unused otherwise)
  u16*   attn  = Qb;
  u16*   combined = Kb;
  const long PBS = (long)Sn * Sn;

  dim3 tb(256);

  // 1. prologue: weights T + bias + rowsum zero + x cvt
  prep_all<<<dim3(9217), tb, 0, stream>>>(Wq, Wk, Wv, Wo, wT, bq, bv, qkvb,
                                          rsum, x, xb);

  if (ws_size >= (73ull << 20)) {
    // 2. QKV: z=0,1 -> Qb,Kb; z=2 -> vt TRANSPOSED (V^T pass eliminated)
    gemm_nt<u16><<<dim3(64, 8, 3), tb, 0, stream>>>(
        xb, nullptr, 0, 1024, wT, 1048576, 1024, Qb, (u16*)nullptr, 8388608, 1024,
        99, 1024, 1.0f, qkvb, 1024, nullptr, 0, 0, vt);
    // 3. scores GEMM (exp + rowsum epilogue) + conv riders (-> Vb)
    post_qkv<<<dim3(1024 + 1024), tb, 0, stream>>>(1024, 1024, Qb, Kb, Pd, Pw,
                                                   Vb, vt, rsum,
                                                   x, cw, cb, conv);
    // 4. PV (512 tiles = 1 clean round, 1/rowsum epilogue)
    pv_conv<<<dim3(512), tb, 0, stream>>>(512, Pd, Pw, vt, attn, rsum,
                                          x, cw, cb, conv);
    // 5. combined = LN2(LN1(conv) + attn)
    ln2_kernel<<<dim3(8192), tb, 0, stream>>>(conv, attn, gamma, beta, combined);
  } else {
    // fallback: classic flow (V written normally, V^T rider pass, softmax)
    gemm_nt<u16><<<dim3(64, 8, 3), tb, 0, stream>>>(
        xb, nullptr, 0, 1024, wT, 1048576, 1024, Qb, (u16*)nullptr, 8388608, 1024,
        99, 1024, 1.0f, qkvb, 1024, nullptr, 0, 0, nullptr);
    post_qkv<<<dim3(2048), tb, 0, stream>>>(0, 0, Qb, Kb, Pd, Pw, Vb, vt, rsum,
                                            x, cw, cb, conv);
    for (int c = 0; c < 2; c++) {
      long off = (long)c * 2 * Sn * Dn;
      gemm_nt<u16><<<dim3(16, 16, 2), tb, 0, stream>>>(
          Qb + off, nullptr, (long)Sn * Dn, 1024, Kb + off, (long)Sn * Dn, 1024,
          Pd, (u16*)nullptr, PBS, 2048,
          99, 1024, 0.03125f, nullptr, 0, nullptr, 0, 0, nullptr);
      smax_conv<<<dim3(4096 + (c == 0 ? 1024 : 0)), tb, 0, stream>>>(
          Pd, Pd, 4096, 4096, x, cw, cb, conv);
      gemm_nt<u16><<<dim3(16, 8, 2), tb, 0, stream>>>(
          Pd, nullptr, PBS, 2048, vt + off, (long)Dn * Sn, 2048,
          attn + off, (u16*)nullptr, (long)Sn * Dn, 1024,
          99, 2048, 1.0f, nullptr, 0, nullptr, 0, 0, nullptr);
    }
    ln2_kernel<<<dim3(8192), tb, 0, stream>>>(conv, attn, gamma, beta, combined);
  }

  // 6. out = combined @ Wo + bo + x
  gemm_nt<float><<<dim3(64, 8, 1), tb, 0, stream>>>(
      combined, nullptr, 0, 1024, wT + 3u * 1048576u, 0, 1024,
      out, (float*)nullptr, 0, 1024,
      99, 1024, 1.0f, bo, 0, x, 0, 1024, nullptr);
}